// Round 1
// baseline (214.127 us; speedup 1.0000x reference)
//
#include <hip/hip_runtime.h>
#include <hip/hip_bf16.h>

// out[b,h,q,kv] = scores[b,h,q,kv] + bias[offset[q]]
// B=2, H=16, W=2048 -> rows = B*H*W = 65536 rows of W floats each.
// Pure HBM-bound streaming add with a per-row scalar bias gather.

__global__ __launch_bounds__(256) void bias_bcast_add_kernel(
    const float4* __restrict__ scores,
    const float*  __restrict__ bias,
    const int*    __restrict__ offset,
    float4*       __restrict__ out,
    int rows, int W) {
    const int vec_per_row = W / 4;              // 512 float4 per row
    for (int row = blockIdx.x; row < rows; row += gridDim.x) {
        const int q = row & (W - 1);            // W is a power of two (2048)
        const float bq = bias[offset[q]];       // tiny, L2/L1-resident broadcast
        const float4* src = scores + (size_t)row * vec_per_row;
        float4*       dst = out    + (size_t)row * vec_per_row;
        for (int j = threadIdx.x; j < vec_per_row; j += blockDim.x) {
            float4 v = src[j];
            v.x += bq; v.y += bq; v.z += bq; v.w += bq;
            dst[j] = v;
        }
    }
}

extern "C" void kernel_launch(void* const* d_in, const int* in_sizes, int n_in,
                              void* d_out, int out_size, void* d_ws, size_t ws_size,
                              hipStream_t stream) {
    const float* scores = (const float*)d_in[0];
    const float* bias   = (const float*)d_in[1];
    const int*   offset = (const int*)d_in[2];   // harness delivers integer inputs as int32
    float* out = (float*)d_out;

    const int W = in_sizes[1];                   // 2048 (bias length == seq len)
    const int rows = (int)(out_size / W);        // B*H*W = 65536

    // 2048 blocks x 256 threads = 8192 waves = 32 waves/CU on 256 CUs.
    const int block = 256;
    const int grid = 2048;
    bias_bcast_add_kernel<<<grid, block, 0, stream>>>(
        (const float4*)scores, bias, offset, (float4*)out, rows, W);
}

// Round 2
// 179.289 us; speedup vs baseline: 1.1943x; 1.1943x over previous
//
#include <hip/hip_runtime.h>

// out[b,h,q,kv] = scores[b,h,q,kv] + bias[offset[q]]
// B=2,H=16,W=2048 -> 65536 rows of 2048 floats. Pure HBM streaming add.
// R2: 2 rows/iter, 4 float4 loads in flight (MLP), nontemporal hints.

typedef float f32x4 __attribute__((ext_vector_type(4)));

// Fast path: W == 2048, block = 256 -> vec_per_row (512) == 2*blockDim.
__global__ __launch_bounds__(256) void bias_bcast_add_fast(
    const f32x4* __restrict__ scores,
    const float* __restrict__ bias,
    const int*   __restrict__ offset,
    f32x4*       __restrict__ out,
    int rows, int W) {
    const int vpr = W >> 2;                       // 512 float4 per row
    const int j  = threadIdx.x;
    const int j2 = j + blockDim.x;
    for (int row = (blockIdx.x << 1); row < rows; row += (gridDim.x << 1)) {
        const float b0 = bias[offset[row & (W - 1)]];
        const float b1 = bias[offset[(row + 1) & (W - 1)]];
        const f32x4* s = scores + (size_t)row * vpr;
        f32x4*       d = out    + (size_t)row * vpr;
        // 4 independent 16B loads in flight per thread before any store.
        f32x4 v00 = __builtin_nontemporal_load(s + j);
        f32x4 v01 = __builtin_nontemporal_load(s + j2);
        f32x4 v10 = __builtin_nontemporal_load(s + vpr + j);
        f32x4 v11 = __builtin_nontemporal_load(s + vpr + j2);
        v00 += b0; v01 += b0; v10 += b1; v11 += b1;
        __builtin_nontemporal_store(v00, d + j);
        __builtin_nontemporal_store(v01, d + j2);
        __builtin_nontemporal_store(v10, d + vpr + j);
        __builtin_nontemporal_store(v11, d + vpr + j2);
    }
}

// Generic fallback (any W divisible by 4).
__global__ __launch_bounds__(256) void bias_bcast_add_generic(
    const f32x4* __restrict__ scores,
    const float* __restrict__ bias,
    const int*   __restrict__ offset,
    f32x4*       __restrict__ out,
    int rows, int W) {
    const int vpr = W >> 2;
    for (int row = blockIdx.x; row < rows; row += gridDim.x) {
        const int q = row % W;
        const float bq = bias[offset[q]];
        const f32x4* s = scores + (size_t)row * vpr;
        f32x4*       d = out    + (size_t)row * vpr;
        for (int jj = threadIdx.x; jj < vpr; jj += blockDim.x) {
            f32x4 v = __builtin_nontemporal_load(s + jj);
            v += bq;
            __builtin_nontemporal_store(v, d + jj);
        }
    }
}

extern "C" void kernel_launch(void* const* d_in, const int* in_sizes, int n_in,
                              void* d_out, int out_size, void* d_ws, size_t ws_size,
                              hipStream_t stream) {
    const float* scores = (const float*)d_in[0];
    const float* bias   = (const float*)d_in[1];
    const int*   offset = (const int*)d_in[2];
    float* out = (float*)d_out;

    const int W = in_sizes[1];            // 2048
    const int rows = (int)(out_size / W); // 65536

    const int block = 256;
    const int grid = 2048;                // 32 waves/CU on 256 CUs
    if (W == 2048 && rows % 2 == 0) {
        bias_bcast_add_fast<<<grid, block, 0, stream>>>(
            (const f32x4*)scores, bias, offset, (f32x4*)out, rows, W);
    } else {
        bias_bcast_add_generic<<<grid, block, 0, stream>>>(
            (const f32x4*)scores, bias, offset, (f32x4*)out, rows, W);
    }
}